// Round 1
// baseline (369.708 us; speedup 1.0000x reference)
//
#include <hip/hip_runtime.h>
#include <stdint.h>

#define BATCH 128
#define PRI   8732
#define NCLS  21
#define NPR   3

// ws layout:
//   [0, KEYS_BYTES)            uint32 keys[BATCH*PRI]   (monotone-mapped bg_loss; 0 for positives)
//   [KEYS_BYTES, +512)         int num_pos[BATCH]
//   [KEYS_BYTES+512, +32)      double acc[4]: 0=mask_sum 1=pos_loss 2=reg_loss 3=neg_loss

__device__ inline float blk_sum_f(float v, volatile float* sred) {
  #pragma unroll
  for (int o = 32; o > 0; o >>= 1) v += __shfl_down(v, o);
  const int w = threadIdx.x >> 6;
  if ((threadIdx.x & 63) == 0) sred[w] = v;
  __syncthreads();
  float r = 0.f;
  if (threadIdx.x == 0) r = sred[0] + sred[1] + sred[2] + sred[3];
  __syncthreads();
  return r;
}

__global__ __launch_bounds__(256)
void k_main(const float* __restrict__ conf, const float* __restrict__ pred,
            const int* __restrict__ labels, const float* __restrict__ gt,
            const float* __restrict__ mask, uint32_t* __restrict__ keys,
            int* __restrict__ num_pos, double* __restrict__ acc)
{
  __shared__ float sconf[256 * NCLS];   // 21504 B
  __shared__ float sred[4];
  const int tid = threadIdx.x;
  const long long base = (long long)blockIdx.x * 256;

  // Coalesced float4 staging of 256 anchors x 21 classes.
  const float4* src = (const float4*)(conf + base * NCLS);
  float4* dst = (float4*)sconf;
  for (int i = tid; i < (256 * NCLS) / 4; i += 256) dst[i] = src[i];
  __syncthreads();

  const long long a = base + tid;
  const float* cv = &sconf[tid * NCLS];   // stride 21: gcd(21,32)=1 -> conflict-free
  float m = cv[0];
  #pragma unroll
  for (int c = 1; c < NCLS; ++c) m = fmaxf(m, cv[c]);
  float s = 0.f;
  #pragma unroll
  for (int c = 0; c < NCLS; ++c) s += __expf(cv[c] - m);
  const float lse = m + __logf(s);
  const int   lab = labels[a];
  const float mk  = mask[a];
  const float bg  = lse - cv[0];          // >= 0 always (lse >= max >= cv[0])
  const bool  pos = lab > 0;

  float ploss = 0.f, rloss = 0.f;
  if (pos) {
    ploss = mk * (lse - cv[lab]);
    const float4 pd = ((const float4*)pred)[a];   // 16B-aligned: a*16 bytes
    const float4 g  = ((const float4*)gt)[a];
    float sl = 0.f, d, ad;
    d = pd.x - g.x; ad = fabsf(d); sl += (ad < 1.f) ? 0.5f * d * d : ad - 0.5f;
    d = pd.y - g.y; ad = fabsf(d); sl += (ad < 1.f) ? 0.5f * d * d : ad - 0.5f;
    d = pd.z - g.z; ad = fabsf(d); sl += (ad < 1.f) ? 0.5f * d * d : ad - 0.5f;
    d = pd.w - g.w; ad = fabsf(d); sl += (ad < 1.f) ? 0.5f * d * d : ad - 0.5f;
    rloss = mk * sl;
    atomicAdd(&num_pos[(int)(a / PRI)], 1);
  }
  // Monotone float->uint map; positives get key 0 (== the -inf mask in the ref).
  keys[a] = pos ? 0u : (__float_as_uint(bg) | 0x80000000u);

  const float tm = blk_sum_f(mk, sred);
  const float tp = blk_sum_f(ploss, sred);
  const float tr = blk_sum_f(rloss, sred);
  if (tid == 0) {
    atomicAdd(&acc[0], (double)tm);
    atomicAdd(&acc[1], (double)tp);
    atomicAdd(&acc[2], (double)tr);
  }
}

// One block per batch row: exact k-th-largest via 32-bit MSB radix select in LDS,
// then sum of top-k values (tie-exact: greater-than sum + (k - g) * threshold).
__global__ __launch_bounds__(256)
void k_select(const uint32_t* __restrict__ keys, const int* __restrict__ num_pos,
              double* __restrict__ acc)
{
  __shared__ uint32_t sk[PRI];          // 34928 B
  __shared__ int    ired[4];
  __shared__ double dred[4];
  __shared__ int    ibc;
  const int tid = threadIdx.x;
  const int b   = blockIdx.x;

  const int np = num_pos[b];
  int k = np * NPR;
  const int nneg = PRI - np;
  if (k > nneg) k = nneg;
  if (k <= 0) return;                   // uniform exit, before any __syncthreads

  const uint32_t* row = keys + (long long)b * PRI;
  for (int i = tid; i < PRI; i += 256) sk[i] = row[i];
  __syncthreads();

  uint32_t cur = 0;
  for (int bit = 31; bit >= 0; --bit) {
    const uint32_t test = cur | (1u << bit);
    int c = 0;
    for (int i = tid; i < PRI; i += 256) c += (sk[i] >= test) ? 1 : 0;
    #pragma unroll
    for (int o = 32; o > 0; o >>= 1) c += __shfl_down(c, o);
    if ((tid & 63) == 0) ired[tid >> 6] = c;
    __syncthreads();
    if (tid == 0) ibc = ired[0] + ired[1] + ired[2] + ired[3];
    __syncthreads();
    if (ibc >= k) cur = test;           // uniform decision; cur ends as exact k-th largest key
  }

  const float thr = __uint_as_float(cur & 0x7fffffffu);
  double ssum = 0.0;
  int g = 0;
  for (int i = tid; i < PRI; i += 256) {
    const uint32_t kk = sk[i];
    if (kk > cur) { ssum += (double)__uint_as_float(kk & 0x7fffffffu); ++g; }
  }
  #pragma unroll
  for (int o = 32; o > 0; o >>= 1) { ssum += __shfl_down(ssum, o); g += __shfl_down(g, o); }
  if ((tid & 63) == 0) { dred[tid >> 6] = ssum; ired[tid >> 6] = g; }
  __syncthreads();
  if (tid == 0) {
    double tot = dred[0] + dred[1] + dred[2] + dred[3];
    const int gcnt = ired[0] + ired[1] + ired[2] + ired[3];
    tot += (double)(k - gcnt) * (double)thr;   // k - gcnt copies of the tied threshold value
    atomicAdd(&acc[3], tot);
  }
}

__global__ void k_final(const double* __restrict__ acc, float* __restrict__ out) {
  if (threadIdx.x == 0 && blockIdx.x == 0) {
    const double ms = acc[0];
    out[0] = (float)(acc[2] / ms);              // regression_loss / all_batch_pos
    out[1] = (float)((acc[1] + acc[3]) / ms);   // confidence_loss / all_batch_pos
  }
}

extern "C" void kernel_launch(void* const* d_in, const int* in_sizes, int n_in,
                              void* d_out, int out_size, void* d_ws, size_t ws_size,
                              hipStream_t stream) {
  const float* conf   = (const float*)d_in[0];
  const float* pred   = (const float*)d_in[1];
  const int*   labels = (const int*)d_in[2];
  const float* gt     = (const float*)d_in[3];
  const float* mask   = (const float*)d_in[4];
  float* out = (float*)d_out;

  char* ws = (char*)d_ws;
  const size_t keys_bytes = (size_t)BATCH * PRI * sizeof(uint32_t);  // 4,470,784
  uint32_t* keys   = (uint32_t*)ws;
  int*     num_pos = (int*)(ws + keys_bytes);
  double*  acc     = (double*)(ws + keys_bytes + 512);

  // Zero the counters/accumulators (ws is re-poisoned to 0xAA before every launch).
  hipMemsetAsync(ws + keys_bytes, 0, 512 + 4 * sizeof(double), stream);

  k_main<<<(BATCH * PRI) / 256, 256, 0, stream>>>(conf, pred, labels, gt, mask,
                                                  keys, num_pos, acc);
  k_select<<<BATCH, 256, 0, stream>>>(keys, num_pos, acc);
  k_final<<<1, 64, 0, stream>>>(acc, out);
}

// Round 2
// 225.928 us; speedup vs baseline: 1.6364x; 1.6364x over previous
//
#include <hip/hip_runtime.h>
#include <stdint.h>

#define BATCH 128
#define PRI   8732
#define NCLS  21
#define NPR   3
#define TOTAL (BATCH * PRI)            // 1,117,696 (divisible by 256)
#define CPB   4                        // chunks (of 256 anchors) per k_main block

// ws layout:
//   [0, KEYS_BYTES)   uint32 keys[BATCH*PRI]  monotone-mapped bg_loss; 0 for positives
//   [KEYS_BYTES, +32) double acc[4]: 0=mask_sum 1=pos_loss 2=reg_loss 3=neg_loss

__global__ __launch_bounds__(256)
void k_main(const float* __restrict__ conf, const float* __restrict__ pred,
            const int* __restrict__ labels, const float* __restrict__ gt,
            const float* __restrict__ mask, uint32_t* __restrict__ keys,
            double* __restrict__ acc)
{
  __shared__ float sconf[256 * NCLS];          // 21504 B -> 7 blocks/CU
  __shared__ float sm_[4], sp_[4], sr_[4];
  const int tid = threadIdx.x;
  const long long blk_base = (long long)blockIdx.x * (256 * CPB);

  float accm = 0.f, accp = 0.f, accr = 0.f;

  for (int ch = 0; ch < CPB; ++ch) {
    const long long cbase = blk_base + (long long)ch * 256;
    if (cbase >= TOTAL) break;                 // uniform per block (TOTAL % 256 == 0)

    // Coalesced float4 staging: 256 anchors x 21 floats = 1344 float4 (cbase*21 % 4 == 0).
    const float4* src = (const float4*)(conf + cbase * NCLS);
    float4* dst = (float4*)sconf;
    #pragma unroll
    for (int i = 0; i < 6; ++i) {
      const int idx = i * 256 + tid;
      if (idx < 1344) dst[idx] = src[idx];
    }
    __syncthreads();

    const long long a = cbase + tid;           // always < TOTAL (chunks are full)
    const float* cv = &sconf[tid * NCLS];      // stride 21: gcd(21,32)=1, <=2-way alias (free)
    float m = cv[0];
    #pragma unroll
    for (int c = 1; c < NCLS; ++c) m = fmaxf(m, cv[c]);
    float s = 0.f;
    #pragma unroll
    for (int c = 0; c < NCLS; ++c) s += __expf(cv[c] - m);
    const float lse = m + __logf(s);
    const int   lab = labels[a];
    const float mk  = mask[a];
    const float bg  = lse - cv[0];             // >= 0 always (lse >= max >= cv[0])
    const bool  pos = lab > 0;

    accm += mk;
    if (pos) {
      accp += mk * (lse - cv[lab]);
      const float4 pd = ((const float4*)pred)[a];
      const float4 g  = ((const float4*)gt)[a];
      float sl = 0.f, d, ad;
      d = pd.x - g.x; ad = fabsf(d); sl += (ad < 1.f) ? 0.5f * d * d : ad - 0.5f;
      d = pd.y - g.y; ad = fabsf(d); sl += (ad < 1.f) ? 0.5f * d * d : ad - 0.5f;
      d = pd.z - g.z; ad = fabsf(d); sl += (ad < 1.f) ? 0.5f * d * d : ad - 0.5f;
      d = pd.w - g.w; ad = fabsf(d); sl += (ad < 1.f) ? 0.5f * d * d : ad - 0.5f;
      accr += mk * sl;
    }
    // Monotone float->uint key; positives get 0 (== -inf mask in the ref).
    keys[a] = pos ? 0u : (__float_as_uint(bg) | 0x80000000u);
    __syncthreads();                           // LDS reuse guard for next chunk
  }

  // One fused 3-way block reduction + 3 f64 atomics per block.
  #pragma unroll
  for (int o = 32; o > 0; o >>= 1) {
    accm += __shfl_down(accm, o);
    accp += __shfl_down(accp, o);
    accr += __shfl_down(accr, o);
  }
  const int w = tid >> 6;
  if ((tid & 63) == 0) { sm_[w] = accm; sp_[w] = accp; sr_[w] = accr; }
  __syncthreads();
  if (tid == 0) {
    atomicAdd(&acc[0], (double)(sm_[0] + sm_[1] + sm_[2] + sm_[3]));
    atomicAdd(&acc[1], (double)(sp_[0] + sp_[1] + sp_[2] + sp_[3]));
    atomicAdd(&acc[2], (double)(sr_[0] + sr_[1] + sr_[2] + sr_[3]));
  }
}

// One block (512 threads) per batch row. Keys live in registers (18/thread).
// np = count of zero keys. Exact k-th-largest key via MSB-first bit search:
// per bit, count = sum of popcll(ballot(key >= test)) -> 1 barrier/bit, 31 bits
// (bit 31 provably set: count(keys >= 2^31) = nneg >= k). Tie-exact sum.
#define SEL_T 512
#define RPT   18                               // 8732 = 512*17 + 28

__global__ __launch_bounds__(SEL_T)
void k_select(const uint32_t* __restrict__ keys, double* __restrict__ acc)
{
  __shared__ int    slots[31 * 8];             // [bit][wave] - no-reuse => 1 barrier/bit
  __shared__ int    ired[8];
  __shared__ double dred[8];
  const int tid  = threadIdx.x;
  const int w    = tid >> 6;
  const int lane = tid & 63;
  const uint32_t* row = keys + (size_t)blockIdx.x * PRI;

  uint32_t kr[RPT];
  #pragma unroll
  for (int r = 0; r < 17; ++r) kr[r] = row[tid + 512 * r];
  kr[17] = (tid < 28) ? row[tid + 8704] : 0u;  // pad 0: never >= test (test >= 2^31)

  // np = zero-key count (pad zeros excluded via tid<28 guard).
  int zc = 0;
  #pragma unroll
  for (int r = 0; r < 17; ++r) zc += (kr[r] == 0u) ? 1 : 0;
  if (tid < 28) zc += (kr[17] == 0u) ? 1 : 0;
  #pragma unroll
  for (int o = 32; o > 0; o >>= 1) zc += __shfl_down(zc, o);
  if (lane == 0) ired[w] = zc;
  __syncthreads();
  int np = 0;
  #pragma unroll
  for (int i = 0; i < 8; ++i) np += ired[i];   // uniform on all threads

  int k = np * NPR;
  const int nneg = PRI - np;
  if (k > nneg) k = nneg;

  if (k > 0) {                                 // uniform branch
    uint32_t cur = 0x80000000u;
    #pragma unroll 1
    for (int bit = 30; bit >= 0; --bit) {
      const uint32_t test = cur | (1u << bit);
      int c = 0;
      #pragma unroll
      for (int r = 0; r < RPT; ++r)
        c += (int)__popcll(__ballot(kr[r] >= test));   // wave-uniform scalar count
      if (lane == 0) slots[bit * 8 + w] = c;
      __syncthreads();
      int tot = 0;
      #pragma unroll
      for (int i = 0; i < 8; ++i) tot += slots[bit * 8 + i];
      if (tot >= k) cur = test;                // uniform decision
    }

    const float thr = __uint_as_float(cur & 0x7fffffffu);
    double ssum = 0.0;
    int g = 0;
    #pragma unroll
    for (int r = 0; r < RPT; ++r) {
      if (kr[r] > cur) { ssum += (double)__uint_as_float(kr[r] & 0x7fffffffu); ++g; }
    }
    #pragma unroll
    for (int o = 32; o > 0; o >>= 1) { ssum += __shfl_down(ssum, o); g += __shfl_down(g, o); }
    if (lane == 0) { dred[w] = ssum; ired[w] = g; }
    __syncthreads();
    if (tid == 0) {
      double tot = 0.0; int gg = 0;
      #pragma unroll
      for (int i = 0; i < 8; ++i) { tot += dred[i]; gg += ired[i]; }
      tot += (double)(k - gg) * (double)thr;   // tied copies at the threshold
      atomicAdd(&acc[3], tot);
    }
  }
}

__global__ void k_final(const double* __restrict__ acc, float* __restrict__ out) {
  if (threadIdx.x == 0 && blockIdx.x == 0) {
    const double ms = acc[0];
    out[0] = (float)(acc[2] / ms);             // regression_loss / all_batch_pos
    out[1] = (float)((acc[1] + acc[3]) / ms);  // confidence_loss / all_batch_pos
  }
}

extern "C" void kernel_launch(void* const* d_in, const int* in_sizes, int n_in,
                              void* d_out, int out_size, void* d_ws, size_t ws_size,
                              hipStream_t stream) {
  const float* conf   = (const float*)d_in[0];
  const float* pred   = (const float*)d_in[1];
  const int*   labels = (const int*)d_in[2];
  const float* gt     = (const float*)d_in[3];
  const float* mask   = (const float*)d_in[4];
  float* out = (float*)d_out;

  char* ws = (char*)d_ws;
  const size_t keys_bytes = (size_t)TOTAL * sizeof(uint32_t);  // 4,470,784 (8-aligned)
  uint32_t* keys = (uint32_t*)ws;
  double*   acc  = (double*)(ws + keys_bytes);

  hipMemsetAsync(ws + keys_bytes, 0, 4 * sizeof(double), stream);

  const int blocks = (TOTAL + 256 * CPB - 1) / (256 * CPB);     // 1092
  k_main<<<blocks, 256, 0, stream>>>(conf, pred, labels, gt, mask, keys, acc);
  k_select<<<BATCH, SEL_T, 0, stream>>>(keys, acc);
  k_final<<<1, 64, 0, stream>>>(acc, out);
}

// Round 3
// 214.114 us; speedup vs baseline: 1.7267x; 1.0552x over previous
//
#include <hip/hip_runtime.h>
#include <stdint.h>

#define BATCH 128
#define PRI   8732
#define NCLS  21
#define NPR   3
#define TOTAL (BATCH * PRI)            // 1,117,696 (divisible by 1024)
#define CPB   4                        // chunks (of 256 anchors) per k_main block
#define NBLK  (TOTAL / (256 * CPB))    // 1092

// ws layout (no memset needed - every slot written unconditionally):
//   [0, KB)          uint32 keys[TOTAL]   monotone-mapped bg_loss; 0 for positives
//   [KB, +4368)      float pm[NBLK]   per-block mask-sum partials
//   [.., +4368)      float pp[NBLK]   per-block pos-loss partials
//   [.., +4368)      float pr[NBLK]   per-block reg-loss partials
//   [.., +1024)      double neg[BATCH] per-row hard-negative loss sums

// ---------------------------------------------------------------------------
// k_main: software-pipelined. Chunk n+1's global loads (conf float4 x6 +
// labels + mask into registers) are issued BEFORE computing chunk n from LDS,
// so global loads stay in flight across the compute phase (Little's law fix).
// ---------------------------------------------------------------------------
__global__ __launch_bounds__(256, 6)
void k_main(const float* __restrict__ conf, const float* __restrict__ pred,
            const int* __restrict__ labels, const float* __restrict__ gt,
            const float* __restrict__ mask, uint32_t* __restrict__ keys,
            float* __restrict__ pm, float* __restrict__ pp, float* __restrict__ pr)
{
  __shared__ float sconf[256 * NCLS];          // 21504 B
  __shared__ float sm_[4], sp_[4], sr_[4];
  const int tid = threadIdx.x;
  const long long blk_base = (long long)blockIdx.x * (256 * CPB);

  // Prologue: prefetch chunk 0 (1344 float4 = 256 anchors x 21 floats).
  float4 pf[6];
  {
    const float4* src = (const float4*)(conf + blk_base * NCLS);
    #pragma unroll
    for (int i = 0; i < 5; ++i) pf[i] = src[i * 256 + tid];
    if (tid < 64) pf[5] = src[1280 + tid];
  }
  int   lab = labels[blk_base + tid];
  float mk  = mask  [blk_base + tid];

  float accm = 0.f, accp = 0.f, accr = 0.f;

  #pragma unroll 1
  for (int ch = 0; ch < CPB; ++ch) {
    const long long cbase = blk_base + (long long)ch * 256;

    // Stage prefetched registers -> LDS.
    float4* dst = (float4*)sconf;
    #pragma unroll
    for (int i = 0; i < 5; ++i) dst[i * 256 + tid] = pf[i];
    if (tid < 64) dst[1280 + tid] = pf[5];
    __syncthreads();

    const long long a = cbase + tid;
    const int   clab = lab;
    const float cmk  = mk;

    // Issue chunk n+1 loads NOW; they fly while we compute chunk n.
    if (ch + 1 < CPB) {
      const float4* nsrc = (const float4*)(conf + (cbase + 256) * NCLS);
      #pragma unroll
      for (int i = 0; i < 5; ++i) pf[i] = nsrc[i * 256 + tid];
      if (tid < 64) pf[5] = nsrc[1280 + tid];
      lab = labels[a + 256];
      mk  = mask  [a + 256];
    }

    const float* cv = &sconf[tid * NCLS];      // stride 21: gcd(21,32)=1, <=2-way alias
    float m = cv[0];
    #pragma unroll
    for (int c = 1; c < NCLS; ++c) m = fmaxf(m, cv[c]);
    float s = 0.f;
    #pragma unroll
    for (int c = 0; c < NCLS; ++c) s += __expf(cv[c] - m);
    const float lse = m + __logf(s);
    const float bg  = lse - cv[0];             // >= 0 always (lse >= max >= cv[0])
    const bool  pos = clab > 0;

    accm += cmk;
    if (pos) {
      accp += cmk * (lse - cv[clab]);
      const float4 pd = ((const float4*)pred)[a];
      const float4 g  = ((const float4*)gt)[a];
      float sl = 0.f, d, ad;
      d = pd.x - g.x; ad = fabsf(d); sl += (ad < 1.f) ? 0.5f * d * d : ad - 0.5f;
      d = pd.y - g.y; ad = fabsf(d); sl += (ad < 1.f) ? 0.5f * d * d : ad - 0.5f;
      d = pd.z - g.z; ad = fabsf(d); sl += (ad < 1.f) ? 0.5f * d * d : ad - 0.5f;
      d = pd.w - g.w; ad = fabsf(d); sl += (ad < 1.f) ? 0.5f * d * d : ad - 0.5f;
      accr += cmk * sl;
    }
    keys[a] = pos ? 0u : (__float_as_uint(bg) | 0x80000000u);
    __syncthreads();                           // LDS reuse guard
  }

  // One fused 3-way block reduction; partials to ws (no global atomics).
  #pragma unroll
  for (int o = 32; o > 0; o >>= 1) {
    accm += __shfl_down(accm, o);
    accp += __shfl_down(accp, o);
    accr += __shfl_down(accr, o);
  }
  const int w = tid >> 6;
  if ((tid & 63) == 0) { sm_[w] = accm; sp_[w] = accp; sr_[w] = accr; }
  __syncthreads();
  if (tid == 0) {
    pm[blockIdx.x] = sm_[0] + sm_[1] + sm_[2] + sm_[3];
    pp[blockIdx.x] = sp_[0] + sp_[1] + sp_[2] + sp_[3];
    pr[blockIdx.x] = sr_[0] + sr_[1] + sr_[2] + sr_[3];
  }
}

// ---------------------------------------------------------------------------
// k_select: one block (512 threads) per batch row, keys register-resident.
// Exact k-th-largest key via MSB-first search, 2 bits per round (3 candidate
// thresholds, counts monotone) -> 16 barriers. Tie-exact top-k sum.
// ---------------------------------------------------------------------------
#define SEL_T 512
#define RPT   18                               // 8732 = 512*17 + 28

__global__ __launch_bounds__(SEL_T)
void k_select(const uint32_t* __restrict__ keys, double* __restrict__ neg)
{
  __shared__ int    slots[16 * 24 + 8];        // fresh region per round
  __shared__ int    ired[8];
  __shared__ double dred[8];
  const int tid  = threadIdx.x;
  const int w    = tid >> 6;
  const int lane = tid & 63;
  const uint32_t* row = keys + (size_t)blockIdx.x * PRI;

  uint32_t kr[RPT];
  #pragma unroll
  for (int r = 0; r < 17; ++r) kr[r] = row[tid + 512 * r];
  kr[17] = (tid < 28) ? row[tid + 8704] : 0u;  // pad 0: never >= any test (tests >= 2^31)

  // np = zero-key count (pad zeros excluded by tid<28 guard).
  int zc = 0;
  #pragma unroll
  for (int r = 0; r < 17; ++r) zc += (kr[r] == 0u) ? 1 : 0;
  if (tid < 28) zc += (kr[17] == 0u) ? 1 : 0;
  #pragma unroll
  for (int o = 32; o > 0; o >>= 1) zc += __shfl_down(zc, o);
  if (lane == 0) ired[w] = zc;
  __syncthreads();
  int np = 0;
  #pragma unroll
  for (int i = 0; i < 8; ++i) np += ired[i];   // uniform

  int k = np * NPR;
  const int nneg = PRI - np;
  if (k > nneg) k = nneg;

  double result = 0.0;
  if (k > 0) {                                 // uniform branch
    uint32_t cur = 0x80000000u;                // bit31 provably set: nneg >= k
    #pragma unroll 1
    for (int bit = 30; bit >= 1; bit -= 2) {
      const int rnd = (30 - bit) >> 1;
      const uint32_t tA = cur | (3u << (bit - 1));  // bits 11
      const uint32_t tB = cur | (1u << bit);        // bits 10
      const uint32_t tC = cur | (1u << (bit - 1));  // bits 01
      int cA = 0, cB = 0, cC = 0;
      #pragma unroll
      for (int r = 0; r < RPT; ++r) {
        cA += (int)__popcll(__ballot(kr[r] >= tA));
        cB += (int)__popcll(__ballot(kr[r] >= tB));
        cC += (int)__popcll(__ballot(kr[r] >= tC));
      }
      if (lane == 0) {
        int* sl = &slots[rnd * 24];
        sl[w] = cA; sl[8 + w] = cB; sl[16 + w] = cC;
      }
      __syncthreads();
      int TA = 0, TB = 0, TC = 0;
      const int* sl = &slots[rnd * 24];
      #pragma unroll
      for (int i = 0; i < 8; ++i) { TA += sl[i]; TB += sl[8 + i]; TC += sl[16 + i]; }
      cur = (TA >= k) ? tA : (TB >= k) ? tB : (TC >= k) ? tC : cur;  // largest v: count(>=v)>=k
    }
    {                                          // final bit 0
      const uint32_t t = cur | 1u;
      int c = 0;
      #pragma unroll
      for (int r = 0; r < RPT; ++r) c += (int)__popcll(__ballot(kr[r] >= t));
      if (lane == 0) slots[16 * 24 + w] = c;
      __syncthreads();
      int tot = 0;
      #pragma unroll
      for (int i = 0; i < 8; ++i) tot += slots[16 * 24 + i];
      if (tot >= k) cur = t;                   // cur == exact k-th largest key
    }

    const float thr = __uint_as_float(cur & 0x7fffffffu);
    double ssum = 0.0;
    int g = 0;
    #pragma unroll
    for (int r = 0; r < RPT; ++r) {
      if (kr[r] > cur) { ssum += (double)__uint_as_float(kr[r] & 0x7fffffffu); ++g; }
    }
    #pragma unroll
    for (int o = 32; o > 0; o >>= 1) { ssum += __shfl_down(ssum, o); g += __shfl_down(g, o); }
    if (lane == 0) { dred[w] = ssum; ired[w] = g; }
    __syncthreads();
    if (tid == 0) {
      double tot = 0.0; int gg = 0;
      #pragma unroll
      for (int i = 0; i < 8; ++i) { tot += dred[i]; gg += ired[i]; }
      result = tot + (double)(k - gg) * (double)thr;  // tied copies at threshold
    }
  }
  if (tid == 0) neg[blockIdx.x] = result;      // unconditional: ws is poisoned
}

// ---------------------------------------------------------------------------
// k_final: reduce per-block partials (double accumulation) + write outputs.
// ---------------------------------------------------------------------------
__global__ __launch_bounds__(256)
void k_final(const float* __restrict__ pm, const float* __restrict__ pp,
             const float* __restrict__ pr, const double* __restrict__ neg,
             float* __restrict__ out)
{
  __shared__ double red[4][4];
  const int tid = threadIdx.x, w = tid >> 6, lane = tid & 63;
  double sm = 0.0, sp = 0.0, sr = 0.0, sn = 0.0;
  for (int i = tid; i < NBLK; i += 256) {
    sm += (double)pm[i]; sp += (double)pp[i]; sr += (double)pr[i];
  }
  if (tid < BATCH) sn = neg[tid];
  #pragma unroll
  for (int o = 32; o > 0; o >>= 1) {
    sm += __shfl_down(sm, o); sp += __shfl_down(sp, o);
    sr += __shfl_down(sr, o); sn += __shfl_down(sn, o);
  }
  if (lane == 0) { red[0][w] = sm; red[1][w] = sp; red[2][w] = sr; red[3][w] = sn; }
  __syncthreads();
  if (tid == 0) {
    double m = 0, p = 0, r = 0, n = 0;
    #pragma unroll
    for (int i = 0; i < 4; ++i) { m += red[0][i]; p += red[1][i]; r += red[2][i]; n += red[3][i]; }
    out[0] = (float)(r / m);                   // regression_loss / all_batch_pos
    out[1] = (float)((p + n) / m);             // confidence_loss / all_batch_pos
  }
}

extern "C" void kernel_launch(void* const* d_in, const int* in_sizes, int n_in,
                              void* d_out, int out_size, void* d_ws, size_t ws_size,
                              hipStream_t stream) {
  const float* conf   = (const float*)d_in[0];
  const float* pred   = (const float*)d_in[1];
  const int*   labels = (const int*)d_in[2];
  const float* gt     = (const float*)d_in[3];
  const float* mask   = (const float*)d_in[4];
  float* out = (float*)d_out;

  char* ws = (char*)d_ws;
  const size_t keys_bytes = (size_t)TOTAL * sizeof(uint32_t);  // 4,470,784 (8-aligned)
  uint32_t* keys = (uint32_t*)ws;
  float*  pm  = (float*)(ws + keys_bytes);
  float*  pp  = pm + NBLK;
  float*  pr  = pp + NBLK;
  double* neg = (double*)(ws + keys_bytes + ((3 * NBLK * sizeof(float) + 7) & ~(size_t)7));

  k_main<<<NBLK, 256, 0, stream>>>(conf, pred, labels, gt, mask, keys, pm, pp, pr);
  k_select<<<BATCH, SEL_T, 0, stream>>>(keys, neg);
  k_final<<<1, 256, 0, stream>>>(pm, pp, pr, neg, out);
}

// Round 4
// 193.567 us; speedup vs baseline: 1.9100x; 1.1061x over previous
//
#include <hip/hip_runtime.h>
#include <stdint.h>

#define BATCH 128
#define PRI   8732
#define NCLS  21
#define NPR   3
#define TOTAL (BATCH * PRI)            // 1,117,696 (divisible by 256)
#define NBLK  (TOTAL / 256)            // 4366

// ws layout (no memset needed - every slot written unconditionally):
//   [0, KB)        uint32 keys[TOTAL]  monotone-mapped bg_loss; 0 for positives
//   [KB, +17464)   float pm[NBLK]      per-block mask-sum partials
//   [.., +17464)   float pp[NBLK]      per-block pos-loss partials
//   [.., +17464)   float pr[NBLK]      per-block reg-loss partials
//   [.., +1024)    double neg[BATCH]   per-row hard-negative loss sums

typedef const __attribute__((address_space(1))) void gv_t;
typedef __attribute__((address_space(3))) void lv_t;

// ---------------------------------------------------------------------------
// k_main: one 256-anchor chunk per block, staged via async global_load_lds
// (width 16, direct HBM->LDS, no VGPR round-trip). Latency hiding comes from
// 7 LDS-resident blocks/CU overlapping, not intra-block pipelining.
// ---------------------------------------------------------------------------
__global__ __launch_bounds__(256)
void k_main(const float* __restrict__ conf, const float* __restrict__ pred,
            const int* __restrict__ labels, const float* __restrict__ gt,
            const float* __restrict__ mask, uint32_t* __restrict__ keys,
            float* __restrict__ pm, float* __restrict__ pp, float* __restrict__ pr)
{
  __shared__ __align__(16) float sconf[256 * NCLS];   // 21504 B -> 7 blocks/CU
  __shared__ float sm_[4], sp_[4], sr_[4];
  const int tid = threadIdx.x;
  const int wv  = tid >> 6;              // wave id (wave-uniform)
  const int ln  = tid & 63;
  const long long base = (long long)blockIdx.x * 256;
  const float4* src4 = (const float4*)(conf + base * NCLS);  // 21504 % 16 == 0 -> aligned

  // Async stage 1344 float4 (256 anchors x 21 floats) directly into LDS.
  // LDS dest is wave-uniform base + lane*16 (contiguous layout required).
  #pragma unroll
  for (int i = 0; i < 5; ++i) {
    __builtin_amdgcn_global_load_lds(
        (gv_t*)(src4 + i * 256 + tid),
        (lv_t*)((float4*)sconf + i * 256 + wv * 64),
        16, 0, 0);
  }
  if (wv == 0) {                          // tail: slots 1280..1343 (wave-uniform branch)
    __builtin_amdgcn_global_load_lds(
        (gv_t*)(src4 + 1280 + ln),
        (lv_t*)((float4*)sconf + 1280),
        16, 0, 0);
  }

  // Independent register loads fly alongside the LDS staging.
  const long long a = base + tid;
  const int   lab = labels[a];
  const float mk  = mask[a];

  __syncthreads();                        // vmcnt drain -> LDS + lab/mk ready

  const float* cv = &sconf[tid * NCLS];   // stride 21: gcd(21,32)=1 -> <=2-way alias (free)
  float m = cv[0];
  #pragma unroll
  for (int c = 1; c < NCLS; ++c) m = fmaxf(m, cv[c]);
  float s = 0.f;
  #pragma unroll
  for (int c = 0; c < NCLS; ++c) s += __expf(cv[c] - m);
  const float lse = m + __logf(s);
  const float bg  = lse - cv[0];          // >= 0 always (lse >= max >= cv[0])
  const bool  pos = lab > 0;

  float accm = mk, accp = 0.f, accr = 0.f;
  if (pos) {
    accp = mk * (lse - cv[lab]);
    const float4 pd = ((const float4*)pred)[a];
    const float4 g  = ((const float4*)gt)[a];
    float sl = 0.f, d, ad;
    d = pd.x - g.x; ad = fabsf(d); sl += (ad < 1.f) ? 0.5f * d * d : ad - 0.5f;
    d = pd.y - g.y; ad = fabsf(d); sl += (ad < 1.f) ? 0.5f * d * d : ad - 0.5f;
    d = pd.z - g.z; ad = fabsf(d); sl += (ad < 1.f) ? 0.5f * d * d : ad - 0.5f;
    d = pd.w - g.w; ad = fabsf(d); sl += (ad < 1.f) ? 0.5f * d * d : ad - 0.5f;
    accr = mk * sl;
  }
  keys[a] = pos ? 0u : (__float_as_uint(bg) | 0x80000000u);  // monotone map; pos -> 0 (-inf)

  // Fused 3-way block reduction; partials to ws (no global atomics).
  #pragma unroll
  for (int o = 32; o > 0; o >>= 1) {
    accm += __shfl_down(accm, o);
    accp += __shfl_down(accp, o);
    accr += __shfl_down(accr, o);
  }
  if (ln == 0) { sm_[wv] = accm; sp_[wv] = accp; sr_[wv] = accr; }
  __syncthreads();
  if (tid == 0) {
    pm[blockIdx.x] = sm_[0] + sm_[1] + sm_[2] + sm_[3];
    pp[blockIdx.x] = sp_[0] + sp_[1] + sp_[2] + sp_[3];
    pr[blockIdx.x] = sr_[0] + sr_[1] + sr_[2] + sr_[3];
  }
}

// ---------------------------------------------------------------------------
// k_select: one block (512 threads) per batch row, keys register-resident.
// Exact k-th-largest key via MSB-first search, 2 bits per round (3 candidate
// thresholds, counts monotone) -> 16 barriers. Tie-exact top-k sum.
// ---------------------------------------------------------------------------
#define SEL_T 512
#define RPT   18                               // 8732 = 512*17 + 28

__global__ __launch_bounds__(SEL_T)
void k_select(const uint32_t* __restrict__ keys, double* __restrict__ neg)
{
  __shared__ int    slots[16 * 24 + 8];        // fresh region per round
  __shared__ int    ired[8];
  __shared__ double dred[8];
  const int tid  = threadIdx.x;
  const int w    = tid >> 6;
  const int lane = tid & 63;
  const uint32_t* row = keys + (size_t)blockIdx.x * PRI;

  uint32_t kr[RPT];
  #pragma unroll
  for (int r = 0; r < 17; ++r) kr[r] = row[tid + 512 * r];
  kr[17] = (tid < 28) ? row[tid + 8704] : 0u;  // pad 0: never >= any test (tests >= 2^31)

  // np = zero-key count (pad zeros excluded by tid<28 guard).
  int zc = 0;
  #pragma unroll
  for (int r = 0; r < 17; ++r) zc += (kr[r] == 0u) ? 1 : 0;
  if (tid < 28) zc += (kr[17] == 0u) ? 1 : 0;
  #pragma unroll
  for (int o = 32; o > 0; o >>= 1) zc += __shfl_down(zc, o);
  if (lane == 0) ired[w] = zc;
  __syncthreads();
  int np = 0;
  #pragma unroll
  for (int i = 0; i < 8; ++i) np += ired[i];   // uniform

  int k = np * NPR;
  const int nneg = PRI - np;
  if (k > nneg) k = nneg;

  double result = 0.0;
  if (k > 0) {                                 // uniform branch
    uint32_t cur = 0x80000000u;                // bit31 provably set: nneg >= k
    #pragma unroll 1
    for (int bit = 30; bit >= 1; bit -= 2) {
      const int rnd = (30 - bit) >> 1;
      const uint32_t tA = cur | (3u << (bit - 1));  // bits 11
      const uint32_t tB = cur | (1u << bit);        // bits 10
      const uint32_t tC = cur | (1u << (bit - 1));  // bits 01
      int cA = 0, cB = 0, cC = 0;
      #pragma unroll
      for (int r = 0; r < RPT; ++r) {
        cA += (int)__popcll(__ballot(kr[r] >= tA));
        cB += (int)__popcll(__ballot(kr[r] >= tB));
        cC += (int)__popcll(__ballot(kr[r] >= tC));
      }
      if (lane == 0) {
        int* sl = &slots[rnd * 24];
        sl[w] = cA; sl[8 + w] = cB; sl[16 + w] = cC;
      }
      __syncthreads();
      int TA = 0, TB = 0, TC = 0;
      const int* sl = &slots[rnd * 24];
      #pragma unroll
      for (int i = 0; i < 8; ++i) { TA += sl[i]; TB += sl[8 + i]; TC += sl[16 + i]; }
      cur = (TA >= k) ? tA : (TB >= k) ? tB : (TC >= k) ? tC : cur;  // largest v: count(>=v)>=k
    }
    {                                          // final bit 0
      const uint32_t t = cur | 1u;
      int c = 0;
      #pragma unroll
      for (int r = 0; r < RPT; ++r) c += (int)__popcll(__ballot(kr[r] >= t));
      if (lane == 0) slots[16 * 24 + w] = c;
      __syncthreads();
      int tot = 0;
      #pragma unroll
      for (int i = 0; i < 8; ++i) tot += slots[16 * 24 + i];
      if (tot >= k) cur = t;                   // cur == exact k-th largest key
    }

    const float thr = __uint_as_float(cur & 0x7fffffffu);
    double ssum = 0.0;
    int g = 0;
    #pragma unroll
    for (int r = 0; r < RPT; ++r) {
      if (kr[r] > cur) { ssum += (double)__uint_as_float(kr[r] & 0x7fffffffu); ++g; }
    }
    #pragma unroll
    for (int o = 32; o > 0; o >>= 1) { ssum += __shfl_down(ssum, o); g += __shfl_down(g, o); }
    if (lane == 0) { dred[w] = ssum; ired[w] = g; }
    __syncthreads();
    if (tid == 0) {
      double tot = 0.0; int gg = 0;
      #pragma unroll
      for (int i = 0; i < 8; ++i) { tot += dred[i]; gg += ired[i]; }
      result = tot + (double)(k - gg) * (double)thr;  // tied copies at threshold
    }
  }
  if (tid == 0) neg[blockIdx.x] = result;      // unconditional: ws is poisoned
}

// ---------------------------------------------------------------------------
// k_final: reduce per-block partials (double accumulation) + write outputs.
// ---------------------------------------------------------------------------
__global__ __launch_bounds__(256)
void k_final(const float* __restrict__ pm, const float* __restrict__ pp,
             const float* __restrict__ pr, const double* __restrict__ neg,
             float* __restrict__ out)
{
  __shared__ double red[4][4];
  const int tid = threadIdx.x, w = tid >> 6, lane = tid & 63;
  double sm = 0.0, sp = 0.0, sr = 0.0, sn = 0.0;
  for (int i = tid; i < NBLK; i += 256) {
    sm += (double)pm[i]; sp += (double)pp[i]; sr += (double)pr[i];
  }
  if (tid < BATCH) sn = neg[tid];
  #pragma unroll
  for (int o = 32; o > 0; o >>= 1) {
    sm += __shfl_down(sm, o); sp += __shfl_down(sp, o);
    sr += __shfl_down(sr, o); sn += __shfl_down(sn, o);
  }
  if (lane == 0) { red[0][w] = sm; red[1][w] = sp; red[2][w] = sr; red[3][w] = sn; }
  __syncthreads();
  if (tid == 0) {
    double m = 0, p = 0, r = 0, n = 0;
    #pragma unroll
    for (int i = 0; i < 4; ++i) { m += red[0][i]; p += red[1][i]; r += red[2][i]; n += red[3][i]; }
    out[0] = (float)(r / m);                   // regression_loss / all_batch_pos
    out[1] = (float)((p + n) / m);             // confidence_loss / all_batch_pos
  }
}

extern "C" void kernel_launch(void* const* d_in, const int* in_sizes, int n_in,
                              void* d_out, int out_size, void* d_ws, size_t ws_size,
                              hipStream_t stream) {
  const float* conf   = (const float*)d_in[0];
  const float* pred   = (const float*)d_in[1];
  const int*   labels = (const int*)d_in[2];
  const float* gt     = (const float*)d_in[3];
  const float* mask   = (const float*)d_in[4];
  float* out = (float*)d_out;

  char* ws = (char*)d_ws;
  const size_t keys_bytes = (size_t)TOTAL * sizeof(uint32_t);  // 4,470,784 (8-aligned)
  uint32_t* keys = (uint32_t*)ws;
  float*  pm  = (float*)(ws + keys_bytes);
  float*  pp  = pm + NBLK;
  float*  pr  = pp + NBLK;
  double* neg = (double*)(ws + keys_bytes + ((3 * NBLK * sizeof(float) + 7) & ~(size_t)7));

  k_main<<<NBLK, 256, 0, stream>>>(conf, pred, labels, gt, mask, keys, pm, pp, pr);
  k_select<<<BATCH, SEL_T, 0, stream>>>(keys, neg);
  k_final<<<1, 256, 0, stream>>>(pm, pp, pr, neg, out);
}